// Round 2
// baseline (1857.995 us; speedup 1.0000x reference)
//
#include <hip/hip_runtime.h>
#include <hip/hip_bf16.h>
#include <math.h>

#define N_TOK 16384
#define DIM   1024
#define HID   4096
#define NEXP  8
#define NPROJ 256
#define CLAMP_MAXD 4.605170185988091
#define CLAMP_MAXF 4.605170185988091f
// margin for bf16-MFMA gating path: logit-diff error sigma ~1.4e-4 -> 2e-3 = 14 sigma
#define TAUB 2e-3f

// tile bookkeeping: sum_e ceil(cnt_e/128) <= 32768/128 + 8 = 264 tiles
#define MAX_TILES 264
#define MAX_ROWS (MAX_TILES*128)      // 33792
#define CHUNK_TILES 66
#define NCHUNK 4
#define CHUNK_ROWS (CHUNK_TILES*128)  // 8448

// meta[] layout (ints)
#define M_CNT   0   // [8] expert counts
#define M_CUR   8   // [8] fill cursors
#define M_ROWST 16  // [9] padded segment row starts
#define M_TILEST 25 // [9] segment tile starts
#define M_TOT   34  // total row tiles
#define M_RED   35  // redo count

typedef __bf16 bf16x8 __attribute__((ext_vector_type(8)));
typedef float  floatx4 __attribute__((ext_vector_type(4)));

__device__ __forceinline__ unsigned short f2bfbits(float f) {
  __hip_bfloat16 b = __float2bfloat16(f);
  union { __hip_bfloat16 b; unsigned short u; } c; c.b = b; return c.u;
}
__device__ __forceinline__ float bf2f(unsigned short u) {
  union { unsigned int u; float f; } c; c.u = ((unsigned int)u) << 16; return c.f;
}
__device__ __forceinline__ float gelu_exact(float z) {
  return 0.5f * z * (1.0f + erff(z * 0.70710678118654752f));
}

// direct global->LDS DMA, 16B per lane. LDS dest must be wave-uniform base;
// HW writes lane i's 16B to base + i*16.
__device__ __forceinline__ void gld16(void* lds, const void* g) {
  __builtin_amdgcn_global_load_lds(
      (const __attribute__((address_space(1))) void*)g,
      (__attribute__((address_space(3))) void*)lds, 16, 0, 0);
}

// ---------------- small prep kernels ----------------

__global__ void k_zero_meta(int* meta) { meta[threadIdx.x] = 0; }

// sim (PROJ,E) fp32 -> simn fp64 + simnf fp32, columns l2-normalized
__global__ __launch_bounds__(256) void k_simn(const float* __restrict__ sim,
                                              double* __restrict__ simn,
                                              float* __restrict__ simnf) {
  __shared__ double norms[NEXP];
  int t = threadIdx.x;
  if (t < NEXP) {
    double s = 0.0;
    for (int j = 0; j < NPROJ; ++j) { double v = (double)sim[j*NEXP + t]; s += v*v; }
    double n = sqrt(s); norms[t] = (n > 1e-12 ? n : 1e-12);
  }
  __syncthreads();
  for (int q = 0; q < (NPROJ*NEXP)/256; ++q) {
    int idx = t + q*256; int e = idx & (NEXP-1);
    double v = (double)sim[idx] / norms[e];
    simn[idx] = v; simnf[idx] = (float)v;
  }
}

// fp32 (Z,R,C) -> bf16 (Z,C,R)
__global__ __launch_bounds__(256) void k_transpose(const float* __restrict__ in,
                                                   unsigned short* __restrict__ out,
                                                   int R, int C) {
  __shared__ float tile[32][33];
  size_t zoff = (size_t)blockIdx.z * (size_t)R * (size_t)C;
  in += zoff; out += zoff;
  int c  = blockIdx.x*32 + threadIdx.x;
  int r0 = blockIdx.y*32 + threadIdx.y;
  #pragma unroll
  for (int i = 0; i < 4; ++i)
    tile[threadIdx.y + i*8][threadIdx.x] = in[(size_t)(r0 + i*8)*C + c];
  __syncthreads();
  int r  = blockIdx.y*32 + threadIdx.x;
  int c0 = blockIdx.x*32 + threadIdx.y;
  #pragma unroll
  for (int i = 0; i < 4; ++i)
    out[(size_t)(c0 + i*8)*R + r] = f2bfbits(tile[threadIdx.x][threadIdx.y + i*8]);
}

// x fp32 -> xbf bf16, pure streaming (96 MB)
__global__ __launch_bounds__(256) void k_tobf16(const float* __restrict__ x,
                                                unsigned short* __restrict__ xbf) {
  const float4* src = (const float4*)x;
  ushort4* dst = (ushort4*)xbf;
  const int n4 = N_TOK*DIM/4;
  for (int i = blockIdx.x*256 + threadIdx.x; i < n4; i += gridDim.x*256) {
    float4 v = src[i];
    ushort4 o; o.x=f2bfbits(v.x); o.y=f2bfbits(v.y); o.z=f2bfbits(v.z); o.w=f2bfbits(v.w);
    dst[i] = o;
  }
}

// ---------------- gating decision from fp32 proj (after MFMA projection) ----------------
// 128 tokens/block, 2 threads/token (one per 128-col half). Margin < TAUB -> fp64 redo.
__global__ __launch_bounds__(256) void k_gate(const float* __restrict__ proj,
    const float* __restrict__ simnf, const float* __restrict__ temp,
    float* __restrict__ gates, int* __restrict__ eidx, int* __restrict__ meta,
    int* __restrict__ redoList) {
  __shared__ float sn[NPROJ*NEXP];   // 8 KB, layout [j][e]
  __shared__ int hist[NEXP];
  int tid = threadIdx.x;
  if (tid < NEXP) hist[tid] = 0;
  #pragma unroll
  for (int q = 0; q < NPROJ*NEXP/256; ++q)
    sn[tid + q*256] = simnf[tid + q*256];
  __syncthreads();
  int token = blockIdx.x * 128 + (tid >> 1);
  int h = tid & 1;
  const float4* pr = (const float4*)(proj + (size_t)token*NPROJ + h*128);
  float s2 = 0.f;
  float lg[8];
  #pragma unroll
  for (int e = 0; e < 8; ++e) lg[e] = 0.f;
  #pragma unroll 4
  for (int j4 = 0; j4 < 32; ++j4) {
    float4 p4 = pr[j4];
    #pragma unroll
    for (int c = 0; c < 4; ++c) {
      float p = ((const float*)&p4)[c];
      s2 += p*p;
      const float* srow = &sn[(h*128 + j4*4 + c)*NEXP];
      float4 sa = *(const float4*)srow;
      float4 sb = *(const float4*)(srow + 4);
      lg[0] += p*sa.x; lg[1] += p*sa.y; lg[2] += p*sa.z; lg[3] += p*sa.w;
      lg[4] += p*sb.x; lg[5] += p*sb.y; lg[6] += p*sb.z; lg[7] += p*sb.w;
    }
  }
  // combine the two halves of each token (lanes t, t^1)
  s2 += __shfl_xor(s2, 1, 64);
  #pragma unroll
  for (int e = 0; e < 8; ++e) lg[e] += __shfl_xor(lg[e], 1, 64);
  if (h == 0) {
    float den = sqrtf(s2); den = fmaxf(den, 1e-12f);
    float l[8];
    #pragma unroll
    for (int e = 0; e < 8; ++e) l[e] = lg[e] / den;
    int iA = 0; float vA = l[0];
    #pragma unroll
    for (int e = 1; e < 8; ++e) if (l[e] > vA) { vA = l[e]; iA = e; }
    int iB = -1; float vB = -1e30f;
    #pragma unroll
    for (int e = 0; e < 8; ++e) if (e != iA && l[e] > vB) { vB = l[e]; iB = e; }
    float vC = -1e30f;
    #pragma unroll
    for (int e = 0; e < 8; ++e) if (e != iA && e != iB && l[e] > vC) vC = l[e];
    if (vB - vC < TAUB) {
      int p = atomicAdd(&meta[M_RED], 1);
      redoList[p] = token;
    } else {
      float esc = expf(fminf(temp[0], CLAMP_MAXF));
      float ex = expf((vB - vA) * esc);
      float g0 = 1.f / (1.f + ex);
      gates[2*token] = g0; gates[2*token+1] = ex / (1.f + ex);
      eidx[2*token] = iA; eidx[2*token+1] = iB;
      atomicAdd(&hist[iA], 1); atomicAdd(&hist[iB], 1);
    }
  }
  __syncthreads();
  if (tid < NEXP && hist[tid] > 0) atomicAdd(&meta[M_CNT + tid], hist[tid]);
}

// ---------------- gating pass 2: fp64 exact redo for marginal tokens ----------------
__global__ __launch_bounds__(256) void k_gredo(const float* __restrict__ x,
    const float* __restrict__ Wp, const float* __restrict__ bp,
    const double* __restrict__ simn, const float* __restrict__ temp,
    float* __restrict__ gates, int* __restrict__ eidx, int* __restrict__ meta,
    const int* __restrict__ redoList) {
  __shared__ double wred[4][9];
  int nredo = meta[M_RED];
  int tid = threadIdx.x, lane = tid & 63, wv = tid >> 6;
  for (int r = blockIdx.x; r < nredo; r += gridDim.x) {
    int i = redoList[r];
    const float* xr = x + (size_t)i*DIM;
    int j = tid;
    double acc = 0.0;
    for (int d = 0; d < DIM; d += 4) {
      float4 xv = *(const float4*)&xr[d];
      acc += (double)xv.x * (double)Wp[(size_t)(d+0)*NPROJ + j];
      acc += (double)xv.y * (double)Wp[(size_t)(d+1)*NPROJ + j];
      acc += (double)xv.z * (double)Wp[(size_t)(d+2)*NPROJ + j];
      acc += (double)xv.w * (double)Wp[(size_t)(d+3)*NPROJ + j];
    }
    double v = acc + (double)bp[j];
    double vals[9];
    vals[0] = v*v;
    #pragma unroll
    for (int e = 0; e < NEXP; ++e) vals[1+e] = v * simn[j*NEXP + e];
    #pragma unroll
    for (int off = 32; off > 0; off >>= 1)
      #pragma unroll
      for (int k = 0; k < 9; ++k) vals[k] += __shfl_xor(vals[k], off, 64);
    if (lane == 0)
      #pragma unroll
      for (int k = 0; k < 9; ++k) wred[wv][k] = vals[k];
    __syncthreads();
    if (tid == 0) {
      double s[9];
      #pragma unroll
      for (int k = 0; k < 9; ++k)
        s[k] = wred[0][k] + wred[1][k] + wred[2][k] + wred[3][k];
      double den = sqrt(s[0]); if (den < 1e-12) den = 1e-12;
      double tp = (double)temp[0]; if (tp > CLAMP_MAXD) tp = CLAMP_MAXD;
      double sc = exp(tp) / den;
      double l[NEXP];
      #pragma unroll
      for (int e = 0; e < NEXP; ++e) l[e] = s[e+1]*sc;
      int iA = 0; double vA = l[0];
      for (int e = 1; e < NEXP; ++e) if (l[e] > vA) { vA = l[e]; iA = e; }
      int iB = -1; double vB = -1e300;
      for (int e = 0; e < NEXP; ++e) if (e != iA && l[e] > vB) { vB = l[e]; iB = e; }
      double ex = exp(vB - vA);
      double g0 = 1.0/(1.0+ex);
      gates[2*i] = (float)g0; gates[2*i+1] = (float)(ex/(1.0+ex));
      eidx[2*i] = iA; eidx[2*i+1] = iB;
      atomicAdd(&meta[M_CNT + iA], 1); atomicAdd(&meta[M_CNT + iB], 1);
    }
    __syncthreads();
  }
}

// ---------------- routing ----------------
__global__ void k_offsets(int* meta) {
  int accT = 0;
  for (int e = 0; e < NEXP; ++e) {
    meta[M_TILEST + e] = accT;
    meta[M_ROWST + e]  = accT * 128;
    accT += (meta[M_CNT + e] + 127) >> 7;
  }
  meta[M_TILEST + NEXP] = accT;
  meta[M_ROWST + NEXP]  = accT * 128;
  meta[M_TOT] = accT;
}

__global__ void k_inittok(int* tok) { tok[blockIdx.x*256 + threadIdx.x] = 0; }

__global__ void k_fill(const int* __restrict__ eidx, int* meta,
                       int* __restrict__ tok, int* __restrict__ rowOf) {
  int i = blockIdx.x*256 + threadIdx.x;
  if (i >= N_TOK) return;
  #pragma unroll
  for (int k = 0; k < 2; ++k) {
    int e = eidx[2*i + k];
    int pos = atomicAdd(&meta[M_CUR + e], 1);
    int row = meta[M_ROWST + e] + pos;
    tok[row] = i;
    rowOf[2*i + k] = row;
  }
}

// ---------------- expert GEMM: 128x128 tile, BK=64, bf16 MFMA 16x16x32 ----------------
// Double-buffered LDS (2x32KB) with counted s_waitcnt vmcnt(8) + raw s_barrier:
// next tile's 8 global_load_lds stay in flight across the barrier (T3/T4).
// Bijective XCD swizzle (m204), row-tile-fastest order: B panel L2-resident/XCD.
// LDS XOR swizzle: 16B group g of row r lives at slot (g ^ (r&7)).
// ACT: 0 = none (bf16 out), 1 = gelu (bf16 out), 2 = proj mode (no expert
// lookup, e=0, fp32 out, no meta bound check -- runs before routing).
union LdsU {
  struct { short A[2][128*64]; short B[2][128*64]; } s;  // 64 KB (2 blocks/CU)
  float C[32*132];                                       // epilogue transpose buffer
};

template<int ACT>
__global__ __launch_bounds__(256) void k_gemm(
    const unsigned short* __restrict__ Abase, const int* __restrict__ rowmap, int aRowOff,
    const unsigned short* __restrict__ Bbase, long bExpStride,
    const float* __restrict__ biasBase, int biasStride,
    unsigned short* __restrict__ Cbase, int ldc, int cRowOff,
    const int* __restrict__ meta, int tileBase, int K, int nty) {
  __shared__ LdsU lds;
  // --- XCD-aware remap: flat dispatch id -> work id W, row-tile fastest ---
  int flat = (int)(blockIdx.y * gridDim.x + blockIdx.x);
  int nwg  = (int)(gridDim.x * gridDim.y);
  int q8 = nwg >> 3, r8 = nwg & 7;
  int xcd = flat & 7, sub = flat >> 3;
  int W = (xcd < r8 ? xcd * (q8 + 1) : r8 * (q8 + 1) + (xcd - r8) * q8) + sub;
  int bx = W / nty;                   // B column panel
  int by = W - bx * nty;              // row tile within panel
  int rt = tileBase + by;
  int e = 0;
  if (ACT != 2) {
    if (rt >= meta[M_TOT]) return;
    #pragma unroll
    for (int q = 1; q < NEXP; ++q) if (rt >= meta[M_TILEST + q]) e = q;
  }
  const unsigned short* Bexp = Bbase + (size_t)e * (size_t)bExpStride;
  int tid = threadIdx.x;
  int lane = tid & 63, wv = tid >> 6, mw = wv >> 1, nw = wv & 1;
  int ntBase = bx * 128;
  // DMA source pointers: instr jj of wave wv covers tile rows wv*32+jj*8 .. +8
  int lr = lane >> 3;   // row within 8-row slab
  int sg = lane & 7;    // stored 16B-slot within row
  const unsigned short* aG[4]; const unsigned short* bG[4];
  #pragma unroll
  for (int jj = 0; jj < 4; ++jj) {
    int r = wv*32 + jj*8 + lr;
    int g = sg ^ (r & 7);          // global group that lands in slot sg
    int grow = rt*128 + r;
    int arow = rowmap ? rowmap[grow] : (grow - aRowOff);
    aG[jj] = Abase + (size_t)arow * (size_t)K + g*8;
    bG[jj] = Bexp + (size_t)(ntBase + r) * (size_t)K + g*8;
  }
  floatx4 acc[4][4];
  #pragma unroll
  for (int mi = 0; mi < 4; ++mi)
    #pragma unroll
    for (int ni = 0; ni < 4; ++ni) acc[mi][ni] = (floatx4){0.f,0.f,0.f,0.f};
  const int nK = K >> 6;
  // prologue: stage tile 0 into buffer 0 (8 loads in flight)
  #pragma unroll
  for (int jj = 0; jj < 4; ++jj) {
    gld16(&lds.s.A[0][(wv*32 + jj*8)*64], aG[jj]);
    gld16(&lds.s.B[0][(wv*32 + jj*8)*64], bG[jj]);
  }
  for (int kt = 0; kt < nK; ++kt) {
    int cur = kt & 1;
    if (kt + 1 < nK) {
      int nxt = cur ^ 1;
      // issue next tile's loads first; they remain in flight across the barrier
      #pragma unroll
      for (int jj = 0; jj < 4; ++jj) {
        gld16(&lds.s.A[nxt][(wv*32 + jj*8)*64], aG[jj] + ((kt + 1) << 6));
        gld16(&lds.s.B[nxt][(wv*32 + jj*8)*64], bG[jj] + ((kt + 1) << 6));
      }
      // wait only for the 8 oldest (current tile's) loads
      asm volatile("s_waitcnt vmcnt(8)" ::: "memory");
    } else {
      asm volatile("s_waitcnt vmcnt(0)" ::: "memory");
    }
    __builtin_amdgcn_s_barrier();   // all waves' current-tile DMA complete
    const short* As = lds.s.A[cur];
    const short* Bs = lds.s.B[cur];
    #pragma unroll
    for (int ks = 0; ks < 2; ++ks) {
      int gk = ks*4 + (lane >> 4);   // 16B k-group index within row
      bf16x8 af[4], bfr[4];
      #pragma unroll
      for (int mi = 0; mi < 4; ++mi) {
        int m = mw*64 + mi*16 + (lane & 15);
        af[mi] = *(const bf16x8*)&As[m*64 + (gk ^ (m & 7))*8];
      }
      #pragma unroll
      for (int ni = 0; ni < 4; ++ni) {
        int n = nw*64 + ni*16 + (lane & 15);
        bfr[ni] = *(const bf16x8*)&Bs[n*64 + (gk ^ (n & 7))*8];
      }
      #pragma unroll
      for (int mi = 0; mi < 4; ++mi)
        #pragma unroll
        for (int ni = 0; ni < 4; ++ni)
          acc[mi][ni] = __builtin_amdgcn_mfma_f32_16x16x32_bf16(af[mi], bfr[ni], acc[mi][ni], 0,0,0);
    }
    __builtin_amdgcn_s_barrier();   // reads done before next iter's DMA overwrites
  }
  // epilogue: per m-subtile, LDS transpose -> bias -> (gelu) -> stores
  const float* bias = biasBase + (size_t)e * (size_t)biasStride + ntBase;
  #pragma unroll
  for (int p = 0; p < 4; ++p) {
    __syncthreads();
    int lrow0 = mw*16 + ((lane>>4)<<2);
    int lcol  = nw*64 + (lane & 15);
    #pragma unroll
    for (int ni = 0; ni < 4; ++ni)
      #pragma unroll
      for (int jj = 0; jj < 4; ++jj)
        lds.C[(lrow0 + jj)*132 + lcol + ni*16] = acc[p][ni][jj];
    __syncthreads();
    #pragma unroll
    for (int q = 0; q < 2; ++q) {
      int lin = tid + q*256;
      int r = lin >> 4, c8 = lin & 15;
      float4 v0 = *(float4*)&lds.C[r*132 + c8*8];
      float4 v1 = *(float4*)&lds.C[r*132 + c8*8 + 4];
      float4 b0 = ((const float4*)bias)[c8*2];
      float4 b1 = ((const float4*)bias)[c8*2 + 1];
      v0.x += b0.x; v0.y += b0.y; v0.z += b0.z; v0.w += b0.w;
      v1.x += b1.x; v1.y += b1.y; v1.z += b1.z; v1.w += b1.w;
      if (ACT == 1) {
        v0.x = gelu_exact(v0.x); v0.y = gelu_exact(v0.y);
        v0.z = gelu_exact(v0.z); v0.w = gelu_exact(v0.w);
        v1.x = gelu_exact(v1.x); v1.y = gelu_exact(v1.y);
        v1.z = gelu_exact(v1.z); v1.w = gelu_exact(v1.w);
      }
      int gm = rt*128 + (r>>4)*64 + p*16 + (r & 15) - cRowOff;
      if (ACT == 2) {
        float* Cf = (float*)Cbase;
        *(float4*)&Cf[(size_t)gm*(size_t)ldc + ntBase + c8*8] = v0;
        *(float4*)&Cf[(size_t)gm*(size_t)ldc + ntBase + c8*8 + 4] = v1;
      } else {
        union { unsigned short u[8]; int4 v; } o;
        o.u[0]=f2bfbits(v0.x); o.u[1]=f2bfbits(v0.y); o.u[2]=f2bfbits(v0.z); o.u[3]=f2bfbits(v0.w);
        o.u[4]=f2bfbits(v1.x); o.u[5]=f2bfbits(v1.y); o.u[6]=f2bfbits(v1.z); o.u[7]=f2bfbits(v1.w);
        *(int4*)&Cbase[(size_t)gm*(size_t)ldc + ntBase + c8*8] = o.v;
      }
    }
  }
}

// ---------------- combine: out = x + g0*f[r0] + g1*f[r1] ----------------
__global__ __launch_bounds__(256) void k_combine(const float* __restrict__ x,
    const unsigned short* __restrict__ f, const int* __restrict__ rowOf,
    const float* __restrict__ gates, float* __restrict__ out) {
  int i = blockIdx.x, t = threadIdx.x;
  int r0 = rowOf[2*i], r1 = rowOf[2*i+1];
  float g0 = gates[2*i], g1 = gates[2*i+1];
  float4 xv = ((const float4*)(x + (size_t)i*DIM))[t];
  ushort4 a = ((const ushort4*)(f + (size_t)r0*DIM))[t];
  ushort4 b = ((const ushort4*)(f + (size_t)r1*DIM))[t];
  float4 o;
  o.x = xv.x + g0*bf2f(a.x) + g1*bf2f(b.x);
  o.y = xv.y + g0*bf2f(a.y) + g1*bf2f(b.y);
  o.z = xv.z + g0*bf2f(a.z) + g1*bf2f(b.z);
  o.w = xv.w + g0*bf2f(a.w) + g1*bf2f(b.w);
  ((float4*)(out + (size_t)i*DIM))[t] = o;
}

// ---------------- launch ----------------
extern "C" void kernel_launch(void* const* d_in, const int* in_sizes, int n_in,
                              void* d_out, int out_size, void* d_ws, size_t ws_size,
                              hipStream_t stream) {
  const float* x    = (const float*)d_in[0];
  const float* Wp   = (const float*)d_in[1];
  const float* bp   = (const float*)d_in[2];
  const float* sim  = (const float*)d_in[3];
  const float* temp = (const float*)d_in[4];
  const float* W1   = (const float*)d_in[5];
  const float* b1   = (const float*)d_in[6];
  const float* W2   = (const float*)d_in[7];
  const float* b2   = (const float*)d_in[8];
  float* out = (float*)d_out;

  // workspace carve (~300 MB total)
  char* w = (char*)d_ws;
  auto carve = [&](size_t bytes) { char* p = w; w += (bytes + 255) & ~(size_t)255; return p; };
  int*            meta = (int*)           carve(64*sizeof(int));
  float*          gates= (float*)         carve((size_t)N_TOK*2*4);
  int*            eidx = (int*)           carve((size_t)N_TOK*2*4);
  int*            rowOf= (int*)           carve((size_t)N_TOK*2*4);
  int*            tok  = (int*)           carve((size_t)MAX_ROWS*4);
  int*            redoL= (int*)           carve((size_t)N_TOK*4);
  double*         simn = (double*)        carve((size_t)NPROJ*NEXP*8);
  float*          simnf= (float*)         carve((size_t)NPROJ*NEXP*4);
  unsigned short* xbf  = (unsigned short*)carve((size_t)N_TOK*DIM*2);
  unsigned short* W1t  = (unsigned short*)carve((size_t)NEXP*HID*DIM*2);
  unsigned short* W2t  = (unsigned short*)carve((size_t)NEXP*DIM*HID*2);
  unsigned short* h    = (unsigned short*)carve((size_t)CHUNK_ROWS*HID*2);
  unsigned short* f    = (unsigned short*)carve((size_t)MAX_ROWS*DIM*2);
  // proj (16 MB fp32) and WpT (512 KB bf16) alias h: h is dead until the chunk loop.
  float*          proj = (float*)h;
  unsigned short* WpT  = (unsigned short*)(h + (size_t)N_TOK*NPROJ*2); // byte off 16 MB

  hipLaunchKernelGGL(k_zero_meta, dim3(1), dim3(64), 0, stream, meta);
  hipLaunchKernelGGL(k_simn, dim3(1), dim3(256), 0, stream, sim, simn, simnf);
  // W1 (E, D, H) -> W1t (E, H, D);  W2 (E, H, D) -> W2t (E, D, H)
  hipLaunchKernelGGL(k_transpose, dim3(HID/32, DIM/32, NEXP), dim3(32,8), 0, stream, W1, W1t, DIM, HID);
  hipLaunchKernelGGL(k_transpose, dim3(DIM/32, HID/32, NEXP), dim3(32,8), 0, stream, W2, W2t, HID, DIM);
  // Wp (D, PROJ) -> WpT (PROJ, D) bf16
  hipLaunchKernelGGL(k_transpose, dim3(NPROJ/32, DIM/32, 1), dim3(32,8), 0, stream, Wp, WpT, DIM, NPROJ);
  // x -> xbf
  hipLaunchKernelGGL(k_tobf16, dim3(2048), dim3(256), 0, stream, x, xbf);
  // proj = xbf @ WpT^T + bp  (fp32 out, MFMA)
  hipLaunchKernelGGL((k_gemm<2>), dim3(NPROJ/128, N_TOK/128), dim3(256), 0, stream,
      xbf, (const int*)nullptr, 0, WpT, 0L, bp, 0,
      (unsigned short*)proj, NPROJ, 0, meta, 0, DIM, N_TOK/128);
  // gating decision
  hipLaunchKernelGGL(k_gate, dim3(N_TOK/128), dim3(256), 0, stream,
                     proj, simnf, temp, gates, eidx, meta, redoL);
  hipLaunchKernelGGL(k_gredo, dim3(128), dim3(256), 0, stream,
                     x, Wp, bp, simn, temp, gates, eidx, meta, redoL);
  hipLaunchKernelGGL(k_offsets, dim3(1), dim3(1), 0, stream, meta);
  hipLaunchKernelGGL(k_inittok, dim3(MAX_ROWS/256), dim3(256), 0, stream, tok);
  hipLaunchKernelGGL(k_fill, dim3(N_TOK/256), dim3(256), 0, stream, eidx, meta, tok, rowOf);
  for (int c = 0; c < NCHUNK; ++c) {
    // GEMM1: h = gelu(gather(xbf) @ W1t[e]^T + b1[e]);  grid x = H tiles, y = row tiles
    hipLaunchKernelGGL((k_gemm<1>), dim3(HID/128, CHUNK_TILES), dim3(256), 0, stream,
        xbf, tok, 0, W1t, (long)HID*DIM, b1, HID,
        h, HID, c*CHUNK_ROWS, meta, c*CHUNK_TILES, DIM, CHUNK_TILES);
    // GEMM2: f = h @ W2t[e]^T + b2[e]
    hipLaunchKernelGGL((k_gemm<0>), dim3(DIM/128, CHUNK_TILES), dim3(256), 0, stream,
        h, (const int*)nullptr, c*CHUNK_ROWS, W2t, (long)DIM*HID, b2, DIM,
        f, DIM, 0, meta, c*CHUNK_TILES, HID, CHUNK_TILES);
  }
  hipLaunchKernelGGL(k_combine, dim3(N_TOK), dim3(256), 0, stream, x, f, rowOf, gates, out);
}

// Round 3
// 1781.533 us; speedup vs baseline: 1.0429x; 1.0429x over previous
//
#include <hip/hip_runtime.h>
#include <hip/hip_bf16.h>
#include <math.h>

#define N_TOK 16384
#define DIM   1024
#define HID   4096
#define NEXP  8
#define NPROJ 256
#define CLAMP_MAXD 4.605170185988091
#define CLAMP_MAXF 4.605170185988091f
// margin for bf16-MFMA gating path: logit-diff error sigma ~2e-4 -> 2e-3 = ~8 sigma
#define TAUB 2e-3f
// margin for fp32 exact tier (same trust level as original fp32 gating path)
#define TAU32 3e-4f

// tile bookkeeping: sum_e ceil(cnt_e/128) <= 32768/128 + 8 = 264 tiles
#define MAX_TILES 264
#define MAX_ROWS (MAX_TILES*128)      // 33792
#define CHUNK_TILES 66
#define NCHUNK 4
#define CHUNK_ROWS (CHUNK_TILES*128)  // 8448

// meta[] layout (ints)
#define M_CNT   0   // [8] expert counts
#define M_CUR   8   // [8] fill cursors
#define M_ROWST 16  // [9] padded segment row starts
#define M_TILEST 25 // [9] segment tile starts
#define M_TOT   34  // total row tiles
#define M_RED   35  // bf16-marginal redo count
#define M_RED2  36  // fp32-marginal redo count

typedef __bf16 bf16x8 __attribute__((ext_vector_type(8)));
typedef float  floatx4 __attribute__((ext_vector_type(4)));

__device__ __forceinline__ unsigned short f2bfbits(float f) {
  __hip_bfloat16 b = __float2bfloat16(f);
  union { __hip_bfloat16 b; unsigned short u; } c; c.b = b; return c.u;
}
__device__ __forceinline__ float bf2f(unsigned short u) {
  union { unsigned int u; float f; } c; c.u = ((unsigned int)u) << 16; return c.f;
}
__device__ __forceinline__ float gelu_exact(float z) {
  return 0.5f * z * (1.0f + erff(z * 0.70710678118654752f));
}

// direct global->LDS DMA, 16B per lane. LDS dest must be wave-uniform base;
// HW writes lane i's 16B to base + i*16.
__device__ __forceinline__ void gld16(void* lds, const void* g) {
  __builtin_amdgcn_global_load_lds(
      (const __attribute__((address_space(1))) void*)g,
      (__attribute__((address_space(3))) void*)lds, 16, 0, 0);
}

// ---------------- small prep kernels ----------------

__global__ void k_zero_meta(int* meta) { meta[threadIdx.x] = 0; }

// sim (PROJ,E) fp32 -> simn fp64 + simnf fp32, columns l2-normalized
__global__ __launch_bounds__(256) void k_simn(const float* __restrict__ sim,
                                              double* __restrict__ simn,
                                              float* __restrict__ simnf) {
  __shared__ double norms[NEXP];
  int t = threadIdx.x;
  if (t < NEXP) {
    double s = 0.0;
    for (int j = 0; j < NPROJ; ++j) { double v = (double)sim[j*NEXP + t]; s += v*v; }
    double n = sqrt(s); norms[t] = (n > 1e-12 ? n : 1e-12);
  }
  __syncthreads();
  for (int q = 0; q < (NPROJ*NEXP)/256; ++q) {
    int idx = t + q*256; int e = idx & (NEXP-1);
    double v = (double)sim[idx] / norms[e];
    simn[idx] = v; simnf[idx] = (float)v;
  }
}

// fp32 (Z,R,C) -> bf16 (Z,C,R)
__global__ __launch_bounds__(256) void k_transpose(const float* __restrict__ in,
                                                   unsigned short* __restrict__ out,
                                                   int R, int C) {
  __shared__ float tile[32][33];
  size_t zoff = (size_t)blockIdx.z * (size_t)R * (size_t)C;
  in += zoff; out += zoff;
  int c  = blockIdx.x*32 + threadIdx.x;
  int r0 = blockIdx.y*32 + threadIdx.y;
  #pragma unroll
  for (int i = 0; i < 4; ++i)
    tile[threadIdx.y + i*8][threadIdx.x] = in[(size_t)(r0 + i*8)*C + c];
  __syncthreads();
  int r  = blockIdx.y*32 + threadIdx.x;
  int c0 = blockIdx.x*32 + threadIdx.y;
  #pragma unroll
  for (int i = 0; i < 4; ++i)
    out[(size_t)(c0 + i*8)*R + r] = f2bfbits(tile[threadIdx.x][threadIdx.y + i*8]);
}

// x fp32 -> xbf bf16, pure streaming (96 MB)
__global__ __launch_bounds__(256) void k_tobf16(const float* __restrict__ x,
                                                unsigned short* __restrict__ xbf) {
  const float4* src = (const float4*)x;
  ushort4* dst = (ushort4*)xbf;
  const int n4 = N_TOK*DIM/4;
  for (int i = blockIdx.x*256 + threadIdx.x; i < n4; i += gridDim.x*256) {
    float4 v = src[i];
    ushort4 o; o.x=f2bfbits(v.x); o.y=f2bfbits(v.y); o.z=f2bfbits(v.z); o.w=f2bfbits(v.w);
    dst[i] = o;
  }
}

// ---------------- gating decision from fp32 proj (after MFMA projection) ----------------
// 128 tokens/block, 2 threads/token (one per 128-col half). Margin < TAUB -> fp32 redo.
__global__ __launch_bounds__(256) void k_gate(const float* __restrict__ proj,
    const float* __restrict__ simnf, const float* __restrict__ temp,
    float* __restrict__ gates, int* __restrict__ eidx, int* __restrict__ meta,
    int* __restrict__ redoList) {
  __shared__ float sn[NPROJ*NEXP];   // 8 KB, layout [j][e]
  __shared__ int hist[NEXP];
  int tid = threadIdx.x;
  if (tid < NEXP) hist[tid] = 0;
  #pragma unroll
  for (int q = 0; q < NPROJ*NEXP/256; ++q)
    sn[tid + q*256] = simnf[tid + q*256];
  __syncthreads();
  int token = blockIdx.x * 128 + (tid >> 1);
  int h = tid & 1;
  const float4* pr = (const float4*)(proj + (size_t)token*NPROJ + h*128);
  float s2 = 0.f;
  float lg[8];
  #pragma unroll
  for (int e = 0; e < 8; ++e) lg[e] = 0.f;
  #pragma unroll 4
  for (int j4 = 0; j4 < 32; ++j4) {
    float4 p4 = pr[j4];
    #pragma unroll
    for (int c = 0; c < 4; ++c) {
      float p = ((const float*)&p4)[c];
      s2 += p*p;
      const float* srow = &sn[(h*128 + j4*4 + c)*NEXP];
      float4 sa = *(const float4*)srow;
      float4 sb = *(const float4*)(srow + 4);
      lg[0] += p*sa.x; lg[1] += p*sa.y; lg[2] += p*sa.z; lg[3] += p*sa.w;
      lg[4] += p*sb.x; lg[5] += p*sb.y; lg[6] += p*sb.z; lg[7] += p*sb.w;
    }
  }
  // combine the two halves of each token (lanes t, t^1)
  s2 += __shfl_xor(s2, 1, 64);
  #pragma unroll
  for (int e = 0; e < 8; ++e) lg[e] += __shfl_xor(lg[e], 1, 64);
  if (h == 0) {
    float den = sqrtf(s2); den = fmaxf(den, 1e-12f);
    float l[8];
    #pragma unroll
    for (int e = 0; e < 8; ++e) l[e] = lg[e] / den;
    int iA = 0; float vA = l[0];
    #pragma unroll
    for (int e = 1; e < 8; ++e) if (l[e] > vA) { vA = l[e]; iA = e; }
    int iB = -1; float vB = -1e30f;
    #pragma unroll
    for (int e = 0; e < 8; ++e) if (e != iA && l[e] > vB) { vB = l[e]; iB = e; }
    float vC = -1e30f;
    #pragma unroll
    for (int e = 0; e < 8; ++e) if (e != iA && e != iB && l[e] > vC) vC = l[e];
    if (vB - vC < TAUB) {
      int p = atomicAdd(&meta[M_RED], 1);
      redoList[p] = token;
    } else {
      float esc = expf(fminf(temp[0], CLAMP_MAXF));
      float ex = expf((vB - vA) * esc);
      float g0 = 1.f / (1.f + ex);
      gates[2*token] = g0; gates[2*token+1] = ex / (1.f + ex);
      eidx[2*token] = iA; eidx[2*token+1] = iB;
      atomicAdd(&hist[iA], 1); atomicAdd(&hist[iB], 1);
    }
  }
  __syncthreads();
  if (tid < NEXP && hist[tid] > 0) atomicAdd(&meta[M_CNT + tid], hist[tid]);
}

// ---------------- gating tier 2: fp32 exact redo, 4 tokens/block ----------------
// Thread j owns proj column j. 16 independent fp32 accumulator chains (4 tokens
// x 4 d-phases) keep this issue-bound, not latency-bound. Tokens still marginal
// at TAU32 fall through to the fp64 tier.
__global__ __launch_bounds__(256) void k_gredo32(const float* __restrict__ x,
    const float* __restrict__ Wp, const float* __restrict__ bp,
    const float* __restrict__ simnf, const float* __restrict__ temp,
    float* __restrict__ gates, int* __restrict__ eidx, int* __restrict__ meta,
    const int* __restrict__ redoList, int* __restrict__ redoList2) {
  __shared__ float wred[4][4][9];   // [wave][token][9]
  int nredo = meta[M_RED];
  int tid = threadIdx.x, lane = tid & 63, wv = tid >> 6;
  int j = tid;
  for (int g = blockIdx.x; g*4 < nredo; g += gridDim.x) {
    int cnt = nredo - g*4; if (cnt > 4) cnt = 4;
    const float* xr[4];
    int tok[4];
    #pragma unroll
    for (int t = 0; t < 4; ++t) {
      int idx = g*4 + t; if (idx > nredo-1) idx = nredo-1;
      tok[t] = redoList[idx];
      xr[t] = x + (size_t)tok[t]*DIM;
    }
    float acc[4][4];
    #pragma unroll
    for (int t = 0; t < 4; ++t)
      #pragma unroll
      for (int q = 0; q < 4; ++q) acc[t][q] = 0.f;
    for (int d = 0; d < DIM; d += 4) {
      float4 xv[4];
      #pragma unroll
      for (int t = 0; t < 4; ++t) xv[t] = *(const float4*)&xr[t][d];
      #pragma unroll
      for (int dd = 0; dd < 4; ++dd) {
        float wpv = Wp[(size_t)(d+dd)*NPROJ + j];
        #pragma unroll
        for (int t = 0; t < 4; ++t)
          acc[t][dd] += ((const float*)&xv[t])[dd] * wpv;
      }
    }
    float snv[8];
    #pragma unroll
    for (int e = 0; e < 8; ++e) snv[e] = simnf[j*NEXP + e];
    float bpj = bp[j];
    #pragma unroll
    for (int t = 0; t < 4; ++t) {
      float v = acc[t][0] + acc[t][1] + acc[t][2] + acc[t][3] + bpj;
      float vals[9];
      vals[0] = v*v;
      #pragma unroll
      for (int e = 0; e < 8; ++e) vals[1+e] = v * snv[e];
      #pragma unroll
      for (int off = 32; off > 0; off >>= 1)
        #pragma unroll
        for (int k = 0; k < 9; ++k) vals[k] += __shfl_xor(vals[k], off, 64);
      if (lane == 0)
        #pragma unroll
        for (int k = 0; k < 9; ++k) wred[wv][t][k] = vals[k];
    }
    __syncthreads();
    if (tid == 0) {
      for (int t = 0; t < cnt; ++t) {
        int i = tok[t];
        float s[9];
        #pragma unroll
        for (int k = 0; k < 9; ++k)
          s[k] = wred[0][t][k] + wred[1][t][k] + wred[2][t][k] + wred[3][t][k];
        float den = sqrtf(s[0]); den = fmaxf(den, 1e-12f);
        float l[8];
        #pragma unroll
        for (int e = 0; e < 8; ++e) l[e] = s[1+e] / den;
        int iA = 0; float vA = l[0];
        #pragma unroll
        for (int e = 1; e < 8; ++e) if (l[e] > vA) { vA = l[e]; iA = e; }
        int iB = -1; float vB = -1e30f;
        #pragma unroll
        for (int e = 0; e < 8; ++e) if (e != iA && l[e] > vB) { vB = l[e]; iB = e; }
        float vC = -1e30f;
        #pragma unroll
        for (int e = 0; e < 8; ++e) if (e != iA && e != iB && l[e] > vC) vC = l[e];
        if (vB - vC < TAU32) {
          int p = atomicAdd(&meta[M_RED2], 1);
          redoList2[p] = i;
        } else {
          float esc = expf(fminf(temp[0], CLAMP_MAXF));
          float ex = expf((vB - vA) * esc);
          float g0 = 1.f / (1.f + ex);
          gates[2*i] = g0; gates[2*i+1] = ex / (1.f + ex);
          eidx[2*i] = iA; eidx[2*i+1] = iB;
          atomicAdd(&meta[M_CNT + iA], 1); atomicAdd(&meta[M_CNT + iB], 1);
        }
      }
    }
    __syncthreads();
  }
}

// ---------------- gating tier 3: fp64 exact redo for fp32-marginal tokens ----------------
__global__ __launch_bounds__(256) void k_gredo64(const float* __restrict__ x,
    const float* __restrict__ Wp, const float* __restrict__ bp,
    const double* __restrict__ simn, const float* __restrict__ temp,
    float* __restrict__ gates, int* __restrict__ eidx, int* __restrict__ meta,
    const int* __restrict__ redoList2) {
  __shared__ double wred[4][9];
  int nredo = meta[M_RED2];
  int tid = threadIdx.x, lane = tid & 63, wv = tid >> 6;
  for (int r = blockIdx.x; r < nredo; r += gridDim.x) {
    int i = redoList2[r];
    const float* xr = x + (size_t)i*DIM;
    int j = tid;
    double a0 = 0.0, a1 = 0.0, a2 = 0.0, a3 = 0.0;  // independent chains
    for (int d = 0; d < DIM; d += 4) {
      float4 xv = *(const float4*)&xr[d];
      a0 += (double)xv.x * (double)Wp[(size_t)(d+0)*NPROJ + j];
      a1 += (double)xv.y * (double)Wp[(size_t)(d+1)*NPROJ + j];
      a2 += (double)xv.z * (double)Wp[(size_t)(d+2)*NPROJ + j];
      a3 += (double)xv.w * (double)Wp[(size_t)(d+3)*NPROJ + j];
    }
    double v = (a0 + a1) + (a2 + a3) + (double)bp[j];
    double vals[9];
    vals[0] = v*v;
    #pragma unroll
    for (int e = 0; e < NEXP; ++e) vals[1+e] = v * simn[j*NEXP + e];
    #pragma unroll
    for (int off = 32; off > 0; off >>= 1)
      #pragma unroll
      for (int k = 0; k < 9; ++k) vals[k] += __shfl_xor(vals[k], off, 64);
    if (lane == 0)
      #pragma unroll
      for (int k = 0; k < 9; ++k) wred[wv][k] = vals[k];
    __syncthreads();
    if (tid == 0) {
      double s[9];
      #pragma unroll
      for (int k = 0; k < 9; ++k)
        s[k] = wred[0][k] + wred[1][k] + wred[2][k] + wred[3][k];
      double den = sqrt(s[0]); if (den < 1e-12) den = 1e-12;
      double tp = (double)temp[0]; if (tp > CLAMP_MAXD) tp = CLAMP_MAXD;
      double sc = exp(tp) / den;
      double l[NEXP];
      #pragma unroll
      for (int e = 0; e < NEXP; ++e) l[e] = s[e+1]*sc;
      int iA = 0; double vA = l[0];
      for (int e = 1; e < NEXP; ++e) if (l[e] > vA) { vA = l[e]; iA = e; }
      int iB = -1; double vB = -1e300;
      for (int e = 0; e < NEXP; ++e) if (e != iA && l[e] > vB) { vB = l[e]; iB = e; }
      double ex = exp(vB - vA);
      double g0 = 1.0/(1.0+ex);
      gates[2*i] = (float)g0; gates[2*i+1] = (float)(ex/(1.0+ex));
      eidx[2*i] = iA; eidx[2*i+1] = iB;
      atomicAdd(&meta[M_CNT + iA], 1); atomicAdd(&meta[M_CNT + iB], 1);
    }
    __syncthreads();
  }
}

// ---------------- routing ----------------
__global__ void k_offsets(int* meta) {
  int accT = 0;
  for (int e = 0; e < NEXP; ++e) {
    meta[M_TILEST + e] = accT;
    meta[M_ROWST + e]  = accT * 128;
    accT += (meta[M_CNT + e] + 127) >> 7;
  }
  meta[M_TILEST + NEXP] = accT;
  meta[M_ROWST + NEXP]  = accT * 128;
  meta[M_TOT] = accT;
}

__global__ void k_inittok(int* tok) { tok[blockIdx.x*256 + threadIdx.x] = 0; }

__global__ void k_fill(const int* __restrict__ eidx, int* meta,
                       int* __restrict__ tok, int* __restrict__ rowOf) {
  int i = blockIdx.x*256 + threadIdx.x;
  if (i >= N_TOK) return;
  #pragma unroll
  for (int k = 0; k < 2; ++k) {
    int e = eidx[2*i + k];
    int pos = atomicAdd(&meta[M_CUR + e], 1);
    int row = meta[M_ROWST + e] + pos;
    tok[row] = i;
    rowOf[2*i + k] = row;
  }
}

// ---------------- expert GEMM: 128x128 tile, BK=64, bf16 MFMA 16x16x32 ----------------
// Double-buffered LDS (2x32KB) with counted s_waitcnt vmcnt(8) + raw s_barrier:
// next tile's 8 global_load_lds stay in flight across the barrier (T3/T4).
// Bijective XCD swizzle (m204), row-tile-fastest order: B panel L2-resident/XCD.
// LDS XOR swizzle: 16B group g of row r lives at slot (g ^ (r&7)).
// ACT: 0 = none (bf16 out), 1 = gelu (bf16 out), 2 = proj mode (no expert
// lookup, e=0, fp32 out, no meta bound check -- runs before routing).
union LdsU {
  struct { short A[2][128*64]; short B[2][128*64]; } s;  // 64 KB (2 blocks/CU)
  float C[32*132];                                       // epilogue transpose buffer
};

template<int ACT>
__global__ __launch_bounds__(256) void k_gemm(
    const unsigned short* __restrict__ Abase, const int* __restrict__ rowmap, int aRowOff,
    const unsigned short* __restrict__ Bbase, long bExpStride,
    const float* __restrict__ biasBase, int biasStride,
    unsigned short* __restrict__ Cbase, int ldc, int cRowOff,
    const int* __restrict__ meta, int tileBase, int K, int nty) {
  __shared__ LdsU lds;
  // --- XCD-aware remap: flat dispatch id -> work id W, row-tile fastest ---
  int flat = (int)(blockIdx.y * gridDim.x + blockIdx.x);
  int nwg  = (int)(gridDim.x * gridDim.y);
  int q8 = nwg >> 3, r8 = nwg & 7;
  int xcd = flat & 7, sub = flat >> 3;
  int W = (xcd < r8 ? xcd * (q8 + 1) : r8 * (q8 + 1) + (xcd - r8) * q8) + sub;
  int bx = W / nty;                   // B column panel
  int by = W - bx * nty;              // row tile within panel
  int rt = tileBase + by;
  int e = 0;
  if (ACT != 2) {
    if (rt >= meta[M_TOT]) return;
    #pragma unroll
    for (int q = 1; q < NEXP; ++q) if (rt >= meta[M_TILEST + q]) e = q;
  }
  const unsigned short* Bexp = Bbase + (size_t)e * (size_t)bExpStride;
  int tid = threadIdx.x;
  int lane = tid & 63, wv = tid >> 6, mw = wv >> 1, nw = wv & 1;
  int ntBase = bx * 128;
  // DMA source pointers: instr jj of wave wv covers tile rows wv*32+jj*8 .. +8
  int lr = lane >> 3;   // row within 8-row slab
  int sg = lane & 7;    // stored 16B-slot within row
  const unsigned short* aG[4]; const unsigned short* bG[4];
  #pragma unroll
  for (int jj = 0; jj < 4; ++jj) {
    int r = wv*32 + jj*8 + lr;
    int g = sg ^ (r & 7);          // global group that lands in slot sg
    int grow = rt*128 + r;
    int arow = rowmap ? rowmap[grow] : (grow - aRowOff);
    aG[jj] = Abase + (size_t)arow * (size_t)K + g*8;
    bG[jj] = Bexp + (size_t)(ntBase + r) * (size_t)K + g*8;
  }
  floatx4 acc[4][4];
  #pragma unroll
  for (int mi = 0; mi < 4; ++mi)
    #pragma unroll
    for (int ni = 0; ni < 4; ++ni) acc[mi][ni] = (floatx4){0.f,0.f,0.f,0.f};
  const int nK = K >> 6;
  // prologue: stage tile 0 into buffer 0 (8 loads in flight)
  #pragma unroll
  for (int jj = 0; jj < 4; ++jj) {
    gld16(&lds.s.A[0][(wv*32 + jj*8)*64], aG[jj]);
    gld16(&lds.s.B[0][(wv*32 + jj*8)*64], bG[jj]);
  }
  for (int kt = 0; kt < nK; ++kt) {
    int cur = kt & 1;
    if (kt + 1 < nK) {
      int nxt = cur ^ 1;
      // issue next tile's loads first; they remain in flight across the barrier
      #pragma unroll
      for (int jj = 0; jj < 4; ++jj) {
        gld16(&lds.s.A[nxt][(wv*32 + jj*8)*64], aG[jj] + ((kt + 1) << 6));
        gld16(&lds.s.B[nxt][(wv*32 + jj*8)*64], bG[jj] + ((kt + 1) << 6));
      }
      // wait only for the 8 oldest (current tile's) loads
      asm volatile("s_waitcnt vmcnt(8)" ::: "memory");
    } else {
      asm volatile("s_waitcnt vmcnt(0)" ::: "memory");
    }
    __builtin_amdgcn_s_barrier();   // all waves' current-tile DMA complete
    const short* As = lds.s.A[cur];
    const short* Bs = lds.s.B[cur];
    #pragma unroll
    for (int ks = 0; ks < 2; ++ks) {
      int gk = ks*4 + (lane >> 4);   // 16B k-group index within row
      bf16x8 af[4], bfr[4];
      #pragma unroll
      for (int mi = 0; mi < 4; ++mi) {
        int m = mw*64 + mi*16 + (lane & 15);
        af[mi] = *(const bf16x8*)&As[m*64 + (gk ^ (m & 7))*8];
      }
      #pragma unroll
      for (int ni = 0; ni < 4; ++ni) {
        int n = nw*64 + ni*16 + (lane & 15);
        bfr[ni] = *(const bf16x8*)&Bs[n*64 + (gk ^ (n & 7))*8];
      }
      #pragma unroll
      for (int mi = 0; mi < 4; ++mi)
        #pragma unroll
        for (int ni = 0; ni < 4; ++ni)
          acc[mi][ni] = __builtin_amdgcn_mfma_f32_16x16x32_bf16(af[mi], bfr[ni], acc[mi][ni], 0,0,0);
    }
    __builtin_amdgcn_s_barrier();   // reads done before next iter's DMA overwrites
  }
  // epilogue: per m-subtile, LDS transpose -> bias -> (gelu) -> stores
  const float* bias = biasBase + (size_t)e * (size_t)biasStride + ntBase;
  #pragma unroll
  for (int p = 0; p < 4; ++p) {
    __syncthreads();
    int lrow0 = mw*16 + ((lane>>4)<<2);
    int lcol  = nw*64 + (lane & 15);
    #pragma unroll
    for (int ni = 0; ni < 4; ++ni)
      #pragma unroll
      for (int jj = 0; jj < 4; ++jj)
        lds.C[(lrow0 + jj)*132 + lcol + ni*16] = acc[p][ni][jj];
    __syncthreads();
    #pragma unroll
    for (int q = 0; q < 2; ++q) {
      int lin = tid + q*256;
      int r = lin >> 4, c8 = lin & 15;
      float4 v0 = *(float4*)&lds.C[r*132 + c8*8];
      float4 v1 = *(float4*)&lds.C[r*132 + c8*8 + 4];
      float4 b0 = ((const float4*)bias)[c8*2];
      float4 b1 = ((const float4*)bias)[c8*2 + 1];
      v0.x += b0.x; v0.y += b0.y; v0.z += b0.z; v0.w += b0.w;
      v1.x += b1.x; v1.y += b1.y; v1.z += b1.z; v1.w += b1.w;
      if (ACT == 1) {
        v0.x = gelu_exact(v0.x); v0.y = gelu_exact(v0.y);
        v0.z = gelu_exact(v0.z); v0.w = gelu_exact(v0.w);
        v1.x = gelu_exact(v1.x); v1.y = gelu_exact(v1.y);
        v1.z = gelu_exact(v1.z); v1.w = gelu_exact(v1.w);
      }
      int gm = rt*128 + (r>>4)*64 + p*16 + (r & 15) - cRowOff;
      if (ACT == 2) {
        float* Cf = (float*)Cbase;
        *(float4*)&Cf[(size_t)gm*(size_t)ldc + ntBase + c8*8] = v0;
        *(float4*)&Cf[(size_t)gm*(size_t)ldc + ntBase + c8*8 + 4] = v1;
      } else {
        union { unsigned short u[8]; int4 v; } o;
        o.u[0]=f2bfbits(v0.x); o.u[1]=f2bfbits(v0.y); o.u[2]=f2bfbits(v0.z); o.u[3]=f2bfbits(v0.w);
        o.u[4]=f2bfbits(v1.x); o.u[5]=f2bfbits(v1.y); o.u[6]=f2bfbits(v1.z); o.u[7]=f2bfbits(v1.w);
        *(int4*)&Cbase[(size_t)gm*(size_t)ldc + ntBase + c8*8] = o.v;
      }
    }
  }
}

// ---------------- combine: out = x + g0*f[r0] + g1*f[r1] ----------------
__global__ __launch_bounds__(256) void k_combine(const float* __restrict__ x,
    const unsigned short* __restrict__ f, const int* __restrict__ rowOf,
    const float* __restrict__ gates, float* __restrict__ out) {
  int i = blockIdx.x, t = threadIdx.x;
  int r0 = rowOf[2*i], r1 = rowOf[2*i+1];
  float g0 = gates[2*i], g1 = gates[2*i+1];
  float4 xv = ((const float4*)(x + (size_t)i*DIM))[t];
  ushort4 a = ((const ushort4*)(f + (size_t)r0*DIM))[t];
  ushort4 b = ((const ushort4*)(f + (size_t)r1*DIM))[t];
  float4 o;
  o.x = xv.x + g0*bf2f(a.x) + g1*bf2f(b.x);
  o.y = xv.y + g0*bf2f(a.y) + g1*bf2f(b.y);
  o.z = xv.z + g0*bf2f(a.z) + g1*bf2f(b.z);
  o.w = xv.w + g0*bf2f(a.w) + g1*bf2f(b.w);
  ((float4*)(out + (size_t)i*DIM))[t] = o;
}

// ---------------- launch ----------------
extern "C" void kernel_launch(void* const* d_in, const int* in_sizes, int n_in,
                              void* d_out, int out_size, void* d_ws, size_t ws_size,
                              hipStream_t stream) {
  const float* x    = (const float*)d_in[0];
  const float* Wp   = (const float*)d_in[1];
  const float* bp   = (const float*)d_in[2];
  const float* sim  = (const float*)d_in[3];
  const float* temp = (const float*)d_in[4];
  const float* W1   = (const float*)d_in[5];
  const float* b1   = (const float*)d_in[6];
  const float* W2   = (const float*)d_in[7];
  const float* b2   = (const float*)d_in[8];
  float* out = (float*)d_out;

  // workspace carve (~300 MB total)
  char* w = (char*)d_ws;
  auto carve = [&](size_t bytes) { char* p = w; w += (bytes + 255) & ~(size_t)255; return p; };
  int*            meta = (int*)           carve(64*sizeof(int));
  float*          gates= (float*)         carve((size_t)N_TOK*2*4);
  int*            eidx = (int*)           carve((size_t)N_TOK*2*4);
  int*            rowOf= (int*)           carve((size_t)N_TOK*2*4);
  int*            tok  = (int*)           carve((size_t)MAX_ROWS*4);
  int*            redoL= (int*)           carve((size_t)N_TOK*4);
  int*            redoL2=(int*)           carve((size_t)N_TOK*4);
  double*         simn = (double*)        carve((size_t)NPROJ*NEXP*8);
  float*          simnf= (float*)         carve((size_t)NPROJ*NEXP*4);
  unsigned short* xbf  = (unsigned short*)carve((size_t)N_TOK*DIM*2);
  unsigned short* W1t  = (unsigned short*)carve((size_t)NEXP*HID*DIM*2);
  unsigned short* W2t  = (unsigned short*)carve((size_t)NEXP*DIM*HID*2);
  unsigned short* h    = (unsigned short*)carve((size_t)CHUNK_ROWS*HID*2);
  unsigned short* f    = (unsigned short*)carve((size_t)MAX_ROWS*DIM*2);
  // proj (16 MB fp32) and WpT (512 KB bf16) alias h: h is dead until the chunk loop.
  float*          proj = (float*)h;
  unsigned short* WpT  = (unsigned short*)(h + (size_t)N_TOK*NPROJ*2); // byte off 16 MB

  hipLaunchKernelGGL(k_zero_meta, dim3(1), dim3(64), 0, stream, meta);
  hipLaunchKernelGGL(k_simn, dim3(1), dim3(256), 0, stream, sim, simn, simnf);
  // W1 (E, D, H) -> W1t (E, H, D);  W2 (E, H, D) -> W2t (E, D, H)
  hipLaunchKernelGGL(k_transpose, dim3(HID/32, DIM/32, NEXP), dim3(32,8), 0, stream, W1, W1t, DIM, HID);
  hipLaunchKernelGGL(k_transpose, dim3(DIM/32, HID/32, NEXP), dim3(32,8), 0, stream, W2, W2t, HID, DIM);
  // Wp (D, PROJ) -> WpT (PROJ, D) bf16
  hipLaunchKernelGGL(k_transpose, dim3(NPROJ/32, DIM/32, 1), dim3(32,8), 0, stream, Wp, WpT, DIM, NPROJ);
  // x -> xbf
  hipLaunchKernelGGL(k_tobf16, dim3(2048), dim3(256), 0, stream, x, xbf);
  // proj = xbf @ WpT^T + bp  (fp32 out, MFMA)
  hipLaunchKernelGGL((k_gemm<2>), dim3(NPROJ/128, N_TOK/128), dim3(256), 0, stream,
      xbf, (const int*)nullptr, 0, WpT, 0L, bp, 0,
      (unsigned short*)proj, NPROJ, 0, meta, 0, DIM, N_TOK/128);
  // gating decision (bf16 tier), then fp32 exact tier, then fp64 tier
  hipLaunchKernelGGL(k_gate, dim3(N_TOK/128), dim3(256), 0, stream,
                     proj, simnf, temp, gates, eidx, meta, redoL);
  hipLaunchKernelGGL(k_gredo32, dim3(256), dim3(256), 0, stream,
                     x, Wp, bp, simnf, temp, gates, eidx, meta, redoL, redoL2);
  hipLaunchKernelGGL(k_gredo64, dim3(64), dim3(256), 0, stream,
                     x, Wp, bp, simn, temp, gates, eidx, meta, redoL2);
  hipLaunchKernelGGL(k_offsets, dim3(1), dim3(1), 0, stream, meta);
  hipLaunchKernelGGL(k_inittok, dim3(MAX_ROWS/256), dim3(256), 0, stream, tok);
  hipLaunchKernelGGL(k_fill, dim3(N_TOK/256), dim3(256), 0, stream, eidx, meta, tok, rowOf);
  for (int c = 0; c < NCHUNK; ++c) {
    // GEMM1: h = gelu(gather(xbf) @ W1t[e]^T + b1[e]);  grid x = H tiles, y = row tiles
    hipLaunchKernelGGL((k_gemm<1>), dim3(HID/128, CHUNK_TILES), dim3(256), 0, stream,
        xbf, tok, 0, W1t, (long)HID*DIM, b1, HID,
        h, HID, c*CHUNK_ROWS, meta, c*CHUNK_TILES, DIM, CHUNK_TILES);
    // GEMM2: f = h @ W2t[e]^T + b2[e]
    hipLaunchKernelGGL((k_gemm<0>), dim3(DIM/128, CHUNK_TILES), dim3(256), 0, stream,
        h, (const int*)nullptr, c*CHUNK_ROWS, W2t, (long)DIM*HID, b2, DIM,
        f, DIM, 0, meta, c*CHUNK_TILES, HID, CHUNK_TILES);
  }
  hipLaunchKernelGGL(k_combine, dim3(N_TOK), dim3(256), 0, stream, x, f, rowOf, gates, out);
}

// Round 4
// 1598.932 us; speedup vs baseline: 1.1620x; 1.1142x over previous
//
#include <hip/hip_runtime.h>
#include <hip/hip_bf16.h>
#include <math.h>

#define N_TOK 16384
#define DIM   1024
#define HID   4096
#define NEXP  8
#define NPROJ 256
#define CLAMP_MAXD 4.605170185988091
#define CLAMP_MAXF 4.605170185988091f
// margin for bf16-MFMA gating path: logit-diff error sigma ~2e-4 -> 2e-3 = ~8 sigma
#define TAUB 2e-3f
// margin for fp32 exact tier (same trust level as original fp32 gating path)
#define TAU32 3e-4f

// tile bookkeeping: sum_e ceil(cnt_e/128) <= 32768/128 + 8 = 264 tiles
#define MAX_TILES 264
#define MAX_ROWS (MAX_TILES*128)      // 33792
#define CHUNK_TILES 66
#define NCHUNK 4
#define CHUNK_ROWS (CHUNK_TILES*128)  // 8448

// meta[] layout (ints)
#define M_CNT   0   // [8] expert counts
#define M_CUR   8   // [8] fill cursors
#define M_ROWST 16  // [9] padded segment row starts
#define M_TILEST 25 // [9] segment tile starts
#define M_TOT   34  // total row tiles
#define M_RED   35  // bf16-marginal redo count
#define M_RED2  36  // fp32-marginal redo count

typedef __bf16 bf16x8 __attribute__((ext_vector_type(8)));
typedef float  floatx4 __attribute__((ext_vector_type(4)));

__device__ __forceinline__ unsigned short f2bfbits(float f) {
  __hip_bfloat16 b = __float2bfloat16(f);
  union { __hip_bfloat16 b; unsigned short u; } c; c.b = b; return c.u;
}
__device__ __forceinline__ float bf2f(unsigned short u) {
  union { unsigned int u; float f; } c; c.u = ((unsigned int)u) << 16; return c.f;
}
__device__ __forceinline__ float gelu_exact(float z) {
  return 0.5f * z * (1.0f + erff(z * 0.70710678118654752f));
}

// direct global->LDS DMA, 16B per lane. LDS dest must be wave-uniform base;
// HW writes lane i's 16B to base + i*16.
__device__ __forceinline__ void gld16(void* lds, const void* g) {
  __builtin_amdgcn_global_load_lds(
      (const __attribute__((address_space(1))) void*)g,
      (__attribute__((address_space(3))) void*)lds, 16, 0, 0);
}

// ---------------- small prep kernels ----------------

__global__ void k_zero_meta(int* meta) { meta[threadIdx.x] = 0; }

// sim (PROJ,E) fp32 -> simn fp64 + simnf fp32, columns l2-normalized
__global__ __launch_bounds__(256) void k_simn(const float* __restrict__ sim,
                                              double* __restrict__ simn,
                                              float* __restrict__ simnf) {
  __shared__ double norms[NEXP];
  int t = threadIdx.x;
  if (t < NEXP) {
    double s = 0.0;
    for (int j = 0; j < NPROJ; ++j) { double v = (double)sim[j*NEXP + t]; s += v*v; }
    double n = sqrt(s); norms[t] = (n > 1e-12 ? n : 1e-12);
  }
  __syncthreads();
  for (int q = 0; q < (NPROJ*NEXP)/256; ++q) {
    int idx = t + q*256; int e = idx & (NEXP-1);
    double v = (double)sim[idx] / norms[e];
    simn[idx] = v; simnf[idx] = (float)v;
  }
}

// fp32 (Z,R,C) -> bf16 (Z,C,R)
__global__ __launch_bounds__(256) void k_transpose(const float* __restrict__ in,
                                                   unsigned short* __restrict__ out,
                                                   int R, int C) {
  __shared__ float tile[32][33];
  size_t zoff = (size_t)blockIdx.z * (size_t)R * (size_t)C;
  in += zoff; out += zoff;
  int c  = blockIdx.x*32 + threadIdx.x;
  int r0 = blockIdx.y*32 + threadIdx.y;
  #pragma unroll
  for (int i = 0; i < 4; ++i)
    tile[threadIdx.y + i*8][threadIdx.x] = in[(size_t)(r0 + i*8)*C + c];
  __syncthreads();
  int r  = blockIdx.y*32 + threadIdx.x;
  int c0 = blockIdx.x*32 + threadIdx.y;
  #pragma unroll
  for (int i = 0; i < 4; ++i)
    out[(size_t)(c0 + i*8)*R + r] = f2bfbits(tile[threadIdx.x][threadIdx.y + i*8]);
}

// x fp32 -> xbf bf16, pure streaming (96 MB)
__global__ __launch_bounds__(256) void k_tobf16(const float* __restrict__ x,
                                                unsigned short* __restrict__ xbf) {
  const float4* src = (const float4*)x;
  ushort4* dst = (ushort4*)xbf;
  const int n4 = N_TOK*DIM/4;
  for (int i = blockIdx.x*256 + threadIdx.x; i < n4; i += gridDim.x*256) {
    float4 v = src[i];
    ushort4 o; o.x=f2bfbits(v.x); o.y=f2bfbits(v.y); o.z=f2bfbits(v.z); o.w=f2bfbits(v.w);
    dst[i] = o;
  }
}

// ---------------- gating decision from fp32 proj (after MFMA projection) ----------------
// 128 tokens/block, 2 threads/token (one per 128-col half). Margin < TAUB -> fp32 redo.
__global__ __launch_bounds__(256) void k_gate(const float* __restrict__ proj,
    const float* __restrict__ simnf, const float* __restrict__ temp,
    float* __restrict__ gates, int* __restrict__ eidx, int* __restrict__ meta,
    int* __restrict__ redoList) {
  __shared__ float sn[NPROJ*NEXP];   // 8 KB, layout [j][e]
  __shared__ int hist[NEXP];
  int tid = threadIdx.x;
  if (tid < NEXP) hist[tid] = 0;
  #pragma unroll
  for (int q = 0; q < NPROJ*NEXP/256; ++q)
    sn[tid + q*256] = simnf[tid + q*256];
  __syncthreads();
  int token = blockIdx.x * 128 + (tid >> 1);
  int h = tid & 1;
  const float4* pr = (const float4*)(proj + (size_t)token*NPROJ + h*128);
  float s2 = 0.f;
  float lg[8];
  #pragma unroll
  for (int e = 0; e < 8; ++e) lg[e] = 0.f;
  #pragma unroll 4
  for (int j4 = 0; j4 < 32; ++j4) {
    float4 p4 = pr[j4];
    #pragma unroll
    for (int c = 0; c < 4; ++c) {
      float p = ((const float*)&p4)[c];
      s2 += p*p;
      const float* srow = &sn[(h*128 + j4*4 + c)*NEXP];
      float4 sa = *(const float4*)srow;
      float4 sb = *(const float4*)(srow + 4);
      lg[0] += p*sa.x; lg[1] += p*sa.y; lg[2] += p*sa.z; lg[3] += p*sa.w;
      lg[4] += p*sb.x; lg[5] += p*sb.y; lg[6] += p*sb.z; lg[7] += p*sb.w;
    }
  }
  // combine the two halves of each token (lanes t, t^1)
  s2 += __shfl_xor(s2, 1, 64);
  #pragma unroll
  for (int e = 0; e < 8; ++e) lg[e] += __shfl_xor(lg[e], 1, 64);
  if (h == 0) {
    float den = sqrtf(s2); den = fmaxf(den, 1e-12f);
    float l[8];
    #pragma unroll
    for (int e = 0; e < 8; ++e) l[e] = lg[e] / den;
    int iA = 0; float vA = l[0];
    #pragma unroll
    for (int e = 1; e < 8; ++e) if (l[e] > vA) { vA = l[e]; iA = e; }
    int iB = -1; float vB = -1e30f;
    #pragma unroll
    for (int e = 0; e < 8; ++e) if (e != iA && l[e] > vB) { vB = l[e]; iB = e; }
    float vC = -1e30f;
    #pragma unroll
    for (int e = 0; e < 8; ++e) if (e != iA && e != iB && l[e] > vC) vC = l[e];
    if (vB - vC < TAUB) {
      int p = atomicAdd(&meta[M_RED], 1);
      redoList[p] = token;
    } else {
      float esc = expf(fminf(temp[0], CLAMP_MAXF));
      float ex = expf((vB - vA) * esc);
      float g0 = 1.f / (1.f + ex);
      gates[2*token] = g0; gates[2*token+1] = ex / (1.f + ex);
      eidx[2*token] = iA; eidx[2*token+1] = iB;
      atomicAdd(&hist[iA], 1); atomicAdd(&hist[iB], 1);
    }
  }
  __syncthreads();
  if (tid < NEXP && hist[tid] > 0) atomicAdd(&meta[M_CNT + tid], hist[tid]);
}

// ---------------- gating tier 2: fp32 exact redo, 4 tokens/block ----------------
__global__ __launch_bounds__(256) void k_gredo32(const float* __restrict__ x,
    const float* __restrict__ Wp, const float* __restrict__ bp,
    const float* __restrict__ simnf, const float* __restrict__ temp,
    float* __restrict__ gates, int* __restrict__ eidx, int* __restrict__ meta,
    const int* __restrict__ redoList, int* __restrict__ redoList2) {
  __shared__ float wred[4][4][9];   // [wave][token][9]
  int nredo = meta[M_RED];
  int tid = threadIdx.x, lane = tid & 63, wv = tid >> 6;
  int j = tid;
  for (int g = blockIdx.x; g*4 < nredo; g += gridDim.x) {
    int cnt = nredo - g*4; if (cnt > 4) cnt = 4;
    const float* xr[4];
    int tok[4];
    #pragma unroll
    for (int t = 0; t < 4; ++t) {
      int idx = g*4 + t; if (idx > nredo-1) idx = nredo-1;
      tok[t] = redoList[idx];
      xr[t] = x + (size_t)tok[t]*DIM;
    }
    float acc[4][4];
    #pragma unroll
    for (int t = 0; t < 4; ++t)
      #pragma unroll
      for (int q = 0; q < 4; ++q) acc[t][q] = 0.f;
    for (int d = 0; d < DIM; d += 4) {
      float4 xv[4];
      #pragma unroll
      for (int t = 0; t < 4; ++t) xv[t] = *(const float4*)&xr[t][d];
      #pragma unroll
      for (int dd = 0; dd < 4; ++dd) {
        float wpv = Wp[(size_t)(d+dd)*NPROJ + j];
        #pragma unroll
        for (int t = 0; t < 4; ++t)
          acc[t][dd] += ((const float*)&xv[t])[dd] * wpv;
      }
    }
    float snv[8];
    #pragma unroll
    for (int e = 0; e < 8; ++e) snv[e] = simnf[j*NEXP + e];
    float bpj = bp[j];
    #pragma unroll
    for (int t = 0; t < 4; ++t) {
      float v = acc[t][0] + acc[t][1] + acc[t][2] + acc[t][3] + bpj;
      float vals[9];
      vals[0] = v*v;
      #pragma unroll
      for (int e = 0; e < 8; ++e) vals[1+e] = v * snv[e];
      #pragma unroll
      for (int off = 32; off > 0; off >>= 1)
        #pragma unroll
        for (int k = 0; k < 9; ++k) vals[k] += __shfl_xor(vals[k], off, 64);
      if (lane == 0)
        #pragma unroll
        for (int k = 0; k < 9; ++k) wred[wv][t][k] = vals[k];
    }
    __syncthreads();
    if (tid == 0) {
      for (int t = 0; t < cnt; ++t) {
        int i = tok[t];
        float s[9];
        #pragma unroll
        for (int k = 0; k < 9; ++k)
          s[k] = wred[0][t][k] + wred[1][t][k] + wred[2][t][k] + wred[3][t][k];
        float den = sqrtf(s[0]); den = fmaxf(den, 1e-12f);
        float l[8];
        #pragma unroll
        for (int e = 0; e < 8; ++e) l[e] = s[1+e] / den;
        int iA = 0; float vA = l[0];
        #pragma unroll
        for (int e = 1; e < 8; ++e) if (l[e] > vA) { vA = l[e]; iA = e; }
        int iB = -1; float vB = -1e30f;
        #pragma unroll
        for (int e = 0; e < 8; ++e) if (e != iA && l[e] > vB) { vB = l[e]; iB = e; }
        float vC = -1e30f;
        #pragma unroll
        for (int e = 0; e < 8; ++e) if (e != iA && e != iB && l[e] > vC) vC = l[e];
        if (vB - vC < TAU32) {
          int p = atomicAdd(&meta[M_RED2], 1);
          redoList2[p] = i;
        } else {
          float esc = expf(fminf(temp[0], CLAMP_MAXF));
          float ex = expf((vB - vA) * esc);
          float g0 = 1.f / (1.f + ex);
          gates[2*i] = g0; gates[2*i+1] = ex / (1.f + ex);
          eidx[2*i] = iA; eidx[2*i+1] = iB;
          atomicAdd(&meta[M_CNT + iA], 1); atomicAdd(&meta[M_CNT + iB], 1);
        }
      }
    }
    __syncthreads();
  }
}

// ---------------- gating tier 3: fp64 exact redo for fp32-marginal tokens ----------------
__global__ __launch_bounds__(256) void k_gredo64(const float* __restrict__ x,
    const float* __restrict__ Wp, const float* __restrict__ bp,
    const double* __restrict__ simn, const float* __restrict__ temp,
    float* __restrict__ gates, int* __restrict__ eidx, int* __restrict__ meta,
    const int* __restrict__ redoList2) {
  __shared__ double wred[4][9];
  int nredo = meta[M_RED2];
  int tid = threadIdx.x, lane = tid & 63, wv = tid >> 6;
  for (int r = blockIdx.x; r < nredo; r += gridDim.x) {
    int i = redoList2[r];
    const float* xr = x + (size_t)i*DIM;
    int j = tid;
    double a0 = 0.0, a1 = 0.0, a2 = 0.0, a3 = 0.0;  // independent chains
    for (int d = 0; d < DIM; d += 4) {
      float4 xv = *(const float4*)&xr[d];
      a0 += (double)xv.x * (double)Wp[(size_t)(d+0)*NPROJ + j];
      a1 += (double)xv.y * (double)Wp[(size_t)(d+1)*NPROJ + j];
      a2 += (double)xv.z * (double)Wp[(size_t)(d+2)*NPROJ + j];
      a3 += (double)xv.w * (double)Wp[(size_t)(d+3)*NPROJ + j];
    }
    double v = (a0 + a1) + (a2 + a3) + (double)bp[j];
    double vals[9];
    vals[0] = v*v;
    #pragma unroll
    for (int e = 0; e < NEXP; ++e) vals[1+e] = v * simn[j*NEXP + e];
    #pragma unroll
    for (int off = 32; off > 0; off >>= 1)
      #pragma unroll
      for (int k = 0; k < 9; ++k) vals[k] += __shfl_xor(vals[k], off, 64);
    if (lane == 0)
      #pragma unroll
      for (int k = 0; k < 9; ++k) wred[wv][k] = vals[k];
    __syncthreads();
    if (tid == 0) {
      double s[9];
      #pragma unroll
      for (int k = 0; k < 9; ++k)
        s[k] = wred[0][k] + wred[1][k] + wred[2][k] + wred[3][k];
      double den = sqrt(s[0]); if (den < 1e-12) den = 1e-12;
      double tp = (double)temp[0]; if (tp > CLAMP_MAXD) tp = CLAMP_MAXD;
      double sc = exp(tp) / den;
      double l[NEXP];
      #pragma unroll
      for (int e = 0; e < NEXP; ++e) l[e] = s[e+1]*sc;
      int iA = 0; double vA = l[0];
      for (int e = 1; e < NEXP; ++e) if (l[e] > vA) { vA = l[e]; iA = e; }
      int iB = -1; double vB = -1e300;
      for (int e = 0; e < NEXP; ++e) if (e != iA && l[e] > vB) { vB = l[e]; iB = e; }
      double ex = exp(vB - vA);
      double g0 = 1.0/(1.0+ex);
      gates[2*i] = (float)g0; gates[2*i+1] = (float)(ex/(1.0+ex));
      eidx[2*i] = iA; eidx[2*i+1] = iB;
      atomicAdd(&meta[M_CNT + iA], 1); atomicAdd(&meta[M_CNT + iB], 1);
    }
    __syncthreads();
  }
}

// ---------------- routing ----------------
__global__ void k_offsets(int* meta) {
  int accT = 0;
  for (int e = 0; e < NEXP; ++e) {
    meta[M_TILEST + e] = accT;
    meta[M_ROWST + e]  = accT * 128;
    accT += (meta[M_CNT + e] + 127) >> 7;
  }
  meta[M_TILEST + NEXP] = accT;
  meta[M_ROWST + NEXP]  = accT * 128;
  meta[M_TOT] = accT;
}

__global__ void k_inittok(int* tok) { tok[blockIdx.x*256 + threadIdx.x] = 0; }

// hierarchical fill: LDS histogram -> one global atomic per (block,expert).
// 512 contended global atomics instead of 32768 (was 184 us of pure
// same-address atomic serialization at ~5.6 ns/op).
__global__ __launch_bounds__(256) void k_fill(const int* __restrict__ eidx, int* meta,
                       int* __restrict__ tok, int* __restrict__ rowOf) {
  __shared__ int lcnt[NEXP];
  __shared__ int lbase[NEXP];
  int tid = threadIdx.x;
  int i = blockIdx.x*256 + tid;
  if (tid < NEXP) lcnt[tid] = 0;
  __syncthreads();
  int e0 = eidx[2*i], e1 = eidx[2*i+1];
  int p0 = atomicAdd(&lcnt[e0], 1);
  int p1 = atomicAdd(&lcnt[e1], 1);
  __syncthreads();
  if (tid < NEXP && lcnt[tid] > 0)
    lbase[tid] = atomicAdd(&meta[M_CUR + tid], lcnt[tid]);
  __syncthreads();
  int r0 = meta[M_ROWST + e0] + lbase[e0] + p0;
  int r1 = meta[M_ROWST + e1] + lbase[e1] + p1;
  tok[r0] = i; tok[r1] = i;
  rowOf[2*i] = r0; rowOf[2*i+1] = r1;
}

// ---------------- expert GEMM: 128x128 tile, BK=64, bf16 MFMA 16x16x32 ----------------
// Double-buffered LDS (2x32KB) with counted s_waitcnt vmcnt(8) + raw s_barrier:
// next tile's 8 global_load_lds stay in flight across the barrier (T3/T4).
// Bijective XCD swizzle (m204), row-tile-fastest order: B panel L2-resident/XCD.
// LDS XOR swizzle: 16B group g of row r lives at slot (g ^ (r&7)).
// ACT: 0 = none (bf16 out), 1 = gelu (bf16 out), 2 = proj mode (no expert
// lookup, e=0, fp32 out, no meta bound check -- runs before routing).
union LdsU {
  struct { short A[2][128*64]; short B[2][128*64]; } s;  // 64 KB (2 blocks/CU)
  float C[32*132];                                       // epilogue transpose buffer
};

template<int ACT>
__global__ __launch_bounds__(256) void k_gemm(
    const unsigned short* __restrict__ Abase, const int* __restrict__ rowmap, int aRowOff,
    const unsigned short* __restrict__ Bbase, long bExpStride,
    const float* __restrict__ biasBase, int biasStride,
    unsigned short* __restrict__ Cbase, int ldc, int cRowOff,
    const int* __restrict__ meta, int tileBase, int K, int nty) {
  __shared__ LdsU lds;
  // --- XCD-aware remap: flat dispatch id -> work id W, row-tile fastest ---
  int flat = (int)(blockIdx.y * gridDim.x + blockIdx.x);
  int nwg  = (int)(gridDim.x * gridDim.y);
  int q8 = nwg >> 3, r8 = nwg & 7;
  int xcd = flat & 7, sub = flat >> 3;
  int W = (xcd < r8 ? xcd * (q8 + 1) : r8 * (q8 + 1) + (xcd - r8) * q8) + sub;
  int bx = W / nty;                   // B column panel
  int by = W - bx * nty;              // row tile within panel
  int rt = tileBase + by;
  int e = 0;
  if (ACT != 2) {
    if (rt >= meta[M_TOT]) return;
    #pragma unroll
    for (int q = 1; q < NEXP; ++q) if (rt >= meta[M_TILEST + q]) e = q;
  }
  const unsigned short* Bexp = Bbase + (size_t)e * (size_t)bExpStride;
  int tid = threadIdx.x;
  int lane = tid & 63, wv = tid >> 6, mw = wv >> 1, nw = wv & 1;
  int ntBase = bx * 128;
  // DMA source pointers: instr jj of wave wv covers tile rows wv*32+jj*8 .. +8
  int lr = lane >> 3;   // row within 8-row slab
  int sg = lane & 7;    // stored 16B-slot within row
  const unsigned short* aG[4]; const unsigned short* bG[4];
  #pragma unroll
  for (int jj = 0; jj < 4; ++jj) {
    int r = wv*32 + jj*8 + lr;
    int g = sg ^ (r & 7);          // global group that lands in slot sg
    int grow = rt*128 + r;
    int arow = rowmap ? rowmap[grow] : (grow - aRowOff);
    aG[jj] = Abase + (size_t)arow * (size_t)K + g*8;
    bG[jj] = Bexp + (size_t)(ntBase + r) * (size_t)K + g*8;
  }
  floatx4 acc[4][4];
  #pragma unroll
  for (int mi = 0; mi < 4; ++mi)
    #pragma unroll
    for (int ni = 0; ni < 4; ++ni) acc[mi][ni] = (floatx4){0.f,0.f,0.f,0.f};
  const int nK = K >> 6;
  // prologue: stage tile 0 into buffer 0 (8 loads in flight)
  #pragma unroll
  for (int jj = 0; jj < 4; ++jj) {
    gld16(&lds.s.A[0][(wv*32 + jj*8)*64], aG[jj]);
    gld16(&lds.s.B[0][(wv*32 + jj*8)*64], bG[jj]);
  }
  for (int kt = 0; kt < nK; ++kt) {
    int cur = kt & 1;
    if (kt + 1 < nK) {
      int nxt = cur ^ 1;
      // issue next tile's loads first; they remain in flight across the barrier
      #pragma unroll
      for (int jj = 0; jj < 4; ++jj) {
        gld16(&lds.s.A[nxt][(wv*32 + jj*8)*64], aG[jj] + ((kt + 1) << 6));
        gld16(&lds.s.B[nxt][(wv*32 + jj*8)*64], bG[jj] + ((kt + 1) << 6));
      }
      // wait only for the 8 oldest (current tile's) loads
      asm volatile("s_waitcnt vmcnt(8)" ::: "memory");
    } else {
      asm volatile("s_waitcnt vmcnt(0)" ::: "memory");
    }
    __builtin_amdgcn_s_barrier();   // all waves' current-tile DMA complete
    const short* As = lds.s.A[cur];
    const short* Bs = lds.s.B[cur];
    #pragma unroll
    for (int ks = 0; ks < 2; ++ks) {
      int gk = ks*4 + (lane >> 4);   // 16B k-group index within row
      bf16x8 af[4], bfr[4];
      #pragma unroll
      for (int mi = 0; mi < 4; ++mi) {
        int m = mw*64 + mi*16 + (lane & 15);
        af[mi] = *(const bf16x8*)&As[m*64 + (gk ^ (m & 7))*8];
      }
      #pragma unroll
      for (int ni = 0; ni < 4; ++ni) {
        int n = nw*64 + ni*16 + (lane & 15);
        bfr[ni] = *(const bf16x8*)&Bs[n*64 + (gk ^ (n & 7))*8];
      }
      #pragma unroll
      for (int mi = 0; mi < 4; ++mi)
        #pragma unroll
        for (int ni = 0; ni < 4; ++ni)
          acc[mi][ni] = __builtin_amdgcn_mfma_f32_16x16x32_bf16(af[mi], bfr[ni], acc[mi][ni], 0,0,0);
    }
    __builtin_amdgcn_s_barrier();   // reads done before next iter's DMA overwrites
  }
  // epilogue: per m-subtile, LDS transpose -> bias -> (gelu) -> stores
  const float* bias = biasBase + (size_t)e * (size_t)biasStride + ntBase;
  #pragma unroll
  for (int p = 0; p < 4; ++p) {
    __syncthreads();
    int lrow0 = mw*16 + ((lane>>4)<<2);
    int lcol  = nw*64 + (lane & 15);
    #pragma unroll
    for (int ni = 0; ni < 4; ++ni)
      #pragma unroll
      for (int jj = 0; jj < 4; ++jj)
        lds.C[(lrow0 + jj)*132 + lcol + ni*16] = acc[p][ni][jj];
    __syncthreads();
    #pragma unroll
    for (int q = 0; q < 2; ++q) {
      int lin = tid + q*256;
      int r = lin >> 4, c8 = lin & 15;
      float4 v0 = *(float4*)&lds.C[r*132 + c8*8];
      float4 v1 = *(float4*)&lds.C[r*132 + c8*8 + 4];
      float4 b0 = ((const float4*)bias)[c8*2];
      float4 b1 = ((const float4*)bias)[c8*2 + 1];
      v0.x += b0.x; v0.y += b0.y; v0.z += b0.z; v0.w += b0.w;
      v1.x += b1.x; v1.y += b1.y; v1.z += b1.z; v1.w += b1.w;
      if (ACT == 1) {
        v0.x = gelu_exact(v0.x); v0.y = gelu_exact(v0.y);
        v0.z = gelu_exact(v0.z); v0.w = gelu_exact(v0.w);
        v1.x = gelu_exact(v1.x); v1.y = gelu_exact(v1.y);
        v1.z = gelu_exact(v1.z); v1.w = gelu_exact(v1.w);
      }
      int gm = rt*128 + (r>>4)*64 + p*16 + (r & 15) - cRowOff;
      if (ACT == 2) {
        float* Cf = (float*)Cbase;
        *(float4*)&Cf[(size_t)gm*(size_t)ldc + ntBase + c8*8] = v0;
        *(float4*)&Cf[(size_t)gm*(size_t)ldc + ntBase + c8*8 + 4] = v1;
      } else {
        union { unsigned short u[8]; int4 v; } o;
        o.u[0]=f2bfbits(v0.x); o.u[1]=f2bfbits(v0.y); o.u[2]=f2bfbits(v0.z); o.u[3]=f2bfbits(v0.w);
        o.u[4]=f2bfbits(v1.x); o.u[5]=f2bfbits(v1.y); o.u[6]=f2bfbits(v1.z); o.u[7]=f2bfbits(v1.w);
        *(int4*)&Cbase[(size_t)gm*(size_t)ldc + ntBase + c8*8] = o.v;
      }
    }
  }
}

// ---------------- combine: out = x + g0*f[r0] + g1*f[r1] ----------------
__global__ __launch_bounds__(256) void k_combine(const float* __restrict__ x,
    const unsigned short* __restrict__ f, const int* __restrict__ rowOf,
    const float* __restrict__ gates, float* __restrict__ out) {
  int i = blockIdx.x, t = threadIdx.x;
  int r0 = rowOf[2*i], r1 = rowOf[2*i+1];
  float g0 = gates[2*i], g1 = gates[2*i+1];
  float4 xv = ((const float4*)(x + (size_t)i*DIM))[t];
  ushort4 a = ((const ushort4*)(f + (size_t)r0*DIM))[t];
  ushort4 b = ((const ushort4*)(f + (size_t)r1*DIM))[t];
  float4 o;
  o.x = xv.x + g0*bf2f(a.x) + g1*bf2f(b.x);
  o.y = xv.y + g0*bf2f(a.y) + g1*bf2f(b.y);
  o.z = xv.z + g0*bf2f(a.z) + g1*bf2f(b.z);
  o.w = xv.w + g0*bf2f(a.w) + g1*bf2f(b.w);
  ((float4*)(out + (size_t)i*DIM))[t] = o;
}

// ---------------- launch ----------------
extern "C" void kernel_launch(void* const* d_in, const int* in_sizes, int n_in,
                              void* d_out, int out_size, void* d_ws, size_t ws_size,
                              hipStream_t stream) {
  const float* x    = (const float*)d_in[0];
  const float* Wp   = (const float*)d_in[1];
  const float* bp   = (const float*)d_in[2];
  const float* sim  = (const float*)d_in[3];
  const float* temp = (const float*)d_in[4];
  const float* W1   = (const float*)d_in[5];
  const float* b1   = (const float*)d_in[6];
  const float* W2   = (const float*)d_in[7];
  const float* b2   = (const float*)d_in[8];
  float* out = (float*)d_out;

  // workspace carve (~300 MB total)
  char* w = (char*)d_ws;
  auto carve = [&](size_t bytes) { char* p = w; w += (bytes + 255) & ~(size_t)255; return p; };
  int*            meta = (int*)           carve(64*sizeof(int));
  float*          gates= (float*)         carve((size_t)N_TOK*2*4);
  int*            eidx = (int*)           carve((size_t)N_TOK*2*4);
  int*            rowOf= (int*)           carve((size_t)N_TOK*2*4);
  int*            tok  = (int*)           carve((size_t)MAX_ROWS*4);
  int*            redoL= (int*)           carve((size_t)N_TOK*4);
  int*            redoL2=(int*)           carve((size_t)N_TOK*4);
  double*         simn = (double*)        carve((size_t)NPROJ*NEXP*8);
  float*          simnf= (float*)         carve((size_t)NPROJ*NEXP*4);
  unsigned short* xbf  = (unsigned short*)carve((size_t)N_TOK*DIM*2);
  unsigned short* W1t  = (unsigned short*)carve((size_t)NEXP*HID*DIM*2);
  unsigned short* W2t  = (unsigned short*)carve((size_t)NEXP*DIM*HID*2);
  unsigned short* h    = (unsigned short*)carve((size_t)CHUNK_ROWS*HID*2);
  unsigned short* f    = (unsigned short*)carve((size_t)MAX_ROWS*DIM*2);
  // proj (16 MB fp32) and WpT (512 KB bf16) alias h: h is dead until the chunk loop.
  float*          proj = (float*)h;
  unsigned short* WpT  = (unsigned short*)(h + (size_t)N_TOK*NPROJ*2); // byte off 16 MB

  hipLaunchKernelGGL(k_zero_meta, dim3(1), dim3(64), 0, stream, meta);
  hipLaunchKernelGGL(k_simn, dim3(1), dim3(256), 0, stream, sim, simn, simnf);
  // W1 (E, D, H) -> W1t (E, H, D);  W2 (E, H, D) -> W2t (E, D, H)
  hipLaunchKernelGGL(k_transpose, dim3(HID/32, DIM/32, NEXP), dim3(32,8), 0, stream, W1, W1t, DIM, HID);
  hipLaunchKernelGGL(k_transpose, dim3(DIM/32, HID/32, NEXP), dim3(32,8), 0, stream, W2, W2t, HID, DIM);
  // Wp (D, PROJ) -> WpT (PROJ, D) bf16
  hipLaunchKernelGGL(k_transpose, dim3(NPROJ/32, DIM/32, 1), dim3(32,8), 0, stream, Wp, WpT, DIM, NPROJ);
  // x -> xbf
  hipLaunchKernelGGL(k_tobf16, dim3(2048), dim3(256), 0, stream, x, xbf);
  // proj = xbf @ WpT^T + bp  (fp32 out, MFMA)
  hipLaunchKernelGGL((k_gemm<2>), dim3(NPROJ/128, N_TOK/128), dim3(256), 0, stream,
      xbf, (const int*)nullptr, 0, WpT, 0L, bp, 0,
      (unsigned short*)proj, NPROJ, 0, meta, 0, DIM, N_TOK/128);
  // gating decision (bf16 tier), then fp32 exact tier, then fp64 tier
  hipLaunchKernelGGL(k_gate, dim3(N_TOK/128), dim3(256), 0, stream,
                     proj, simnf, temp, gates, eidx, meta, redoL);
  hipLaunchKernelGGL(k_gredo32, dim3(256), dim3(256), 0, stream,
                     x, Wp, bp, simnf, temp, gates, eidx, meta, redoL, redoL2);
  hipLaunchKernelGGL(k_gredo64, dim3(64), dim3(256), 0, stream,
                     x, Wp, bp, simn, temp, gates, eidx, meta, redoL2);
  hipLaunchKernelGGL(k_offsets, dim3(1), dim3(1), 0, stream, meta);
  hipLaunchKernelGGL(k_inittok, dim3(MAX_ROWS/256), dim3(256), 0, stream, tok);
  hipLaunchKernelGGL(k_fill, dim3(N_TOK/256), dim3(256), 0, stream, eidx, meta, tok, rowOf);
  for (int c = 0; c < NCHUNK; ++c) {
    // GEMM1: h = gelu(gather(xbf) @ W1t[e]^T + b1[e]);  grid x = H tiles, y = row tiles
    hipLaunchKernelGGL((k_gemm<1>), dim3(HID/128, CHUNK_TILES), dim3(256), 0, stream,
        xbf, tok, 0, W1t, (long)HID*DIM, b1, HID,
        h, HID, c*CHUNK_ROWS, meta, c*CHUNK_TILES, DIM, CHUNK_TILES);
    // GEMM2: f = h @ W2t[e]^T + b2[e]
    hipLaunchKernelGGL((k_gemm<0>), dim3(DIM/128, CHUNK_TILES), dim3(256), 0, stream,
        h, (const int*)nullptr, c*CHUNK_ROWS, W2t, (long)DIM*HID, b2, DIM,
        f, DIM, 0, meta, c*CHUNK_TILES, HID, CHUNK_TILES);
  }
  hipLaunchKernelGGL(k_combine, dim3(N_TOK), dim3(256), 0, stream, x, f, rowOf, gates, out);
}